// Round 12
// baseline (340.479 us; speedup 1.0000x reference)
//
#include <hip/hip_runtime.h>

#define HID 32
#define SEQ 512
#define WAVES_PER_BLOCK 4
#define BLOCK (WAVES_PER_BLOCK * 64)

typedef float v2f __attribute__((ext_vector_type(2)));

// ---------------------------------------------------------------------------
// ONE WAVE = FOUR SAMPLES, two "chains" A and B (each chain = 2 samples via
// the two 32-lane halves; lane (s,u) owns all 4 gates of unit u).
// Weights are SHARED by both chains: 128 floats in v128..v255, preloaded once.
// The inner loop interleaves the chains half-a-step out of phase:
//   SLOT(X,Y) = X-chain MAC(33 pk_fma + rolling h-quad reads)
//               interleaved with Y-chain activation tail.
// TLP-2 (rounds 9/10) left 25% idle because the two co-resident waves
// phase-lock and stall together; this schedule hides every trans/LDS latency
// under the other chain's MACs deterministically (ILP), at 1 wave/SIMD.
// Per-sample op sequence is bitwise-identical to rounds 9/10 (absmax 0.0).
// Register map: A: quads v64..79, acc v[80:81] (pi,pf) v[82:83] (pg,po),
// x v[84:85], temps v86..92. B: quads v96..111, acc v112..115, x v116..117,
// temps v118..124. Weights: (wi,wf)[j]=v[128+2j], (wg,wo)[j]=v[192+2j].
// All x values staged to LDS up front (no global traffic in the loop).
// Round-12 fix: SLOT must be invoked through a variadic trampoline (SLOTX)
// so the ARG bundles prescan-expand before the 37-parameter count check.
// ---------------------------------------------------------------------------

// One j-pair of MACs (j=2m,2m+1): validated op_sel splat forms (rounds 4-10):
//   op_sel_hi:[1,0,1]                -> both gate-halves multiply by HP.lo
//   op_sel:[0,1,0] op_sel_hi:[1,1,1] -> both gate-halves multiply by HP.hi
#define GRP(AIF, AGO, WA, WB, WC, WD, HP) \
  "v_pk_fma_f32 v[" AIF "], v[" WA "], v[" HP "], v[" AIF "] op_sel_hi:[1,0,1]\n\t" \
  "v_pk_fma_f32 v[" AGO "], v[" WC "], v[" HP "], v[" AGO "] op_sel_hi:[1,0,1]\n\t" \
  "v_pk_fma_f32 v[" AIF "], v[" WB "], v[" HP "], v[" AIF "] op_sel:[0,1,0] op_sel_hi:[1,1,1]\n\t" \
  "v_pk_fma_f32 v[" AGO "], v[" WD "], v[" HP "], v[" AGO "] op_sel:[0,1,0] op_sel_hi:[1,1,1]\n\t"

// X = MAC chain (acc pairs XIF/XGO, quads XQ0-3, pairs XP0-7, x pair XXP,
// x addr XXA, h row XHR). Y = act chain (acc singles YI/YF/YG/YO, temps
// YU0-6, c/h operands YC/YH, h-write addr YHW; end: write h + issue Y's
// read2 + first 4 h-quads for its next MAC).
// lgkm accounting: slot starts with X's write+read2+q0..q3 outstanding;
// wait(4) drains write+read2, each wait(3) retires the next quad while a
// re-read is issued; wait(2)/(1)/(0) drain the refills. Y's DS ops are all
// issued after X's lgkmcnt(0), so counts never mix.
#define SLOT(XIF,XGO, XQ0,XQ1,XQ2,XQ3, XP0,XP1,XP2,XP3,XP4,XP5,XP6,XP7, XXP, XXA, XHR, \
             YI,YF,YG,YO, YU0,YU1,YU2,YU3,YU4,YU5,YU6, YC,YH, YHW, YXP, YXA, YHR, YQ0,YQ1,YQ2,YQ3) \
  "v_mul_f32 v" YU0 ", 0xbfb8aa3b, v" YI "\n\t" \
  "v_mul_f32 v" YU1 ", 0xbfb8aa3b, v" YF "\n\t" \
  "v_exp_f32 v" YU0 ", v" YU0 "\n\t" \
  "v_exp_f32 v" YU1 ", v" YU1 "\n\t" \
  "v_mul_f32 v" YU2 ", 0x4038aa3b, v" YG "\n\t" \
  "v_mul_f32 v" YU3 ", 0xbfb8aa3b, v" YO "\n\t" \
  "v_exp_f32 v" YU2 ", v" YU2 "\n\t" \
  "v_exp_f32 v" YU3 ", v" YU3 "\n\t" \
  "s_waitcnt lgkmcnt(4)\n\t" \
  "v_pk_fma_f32 v[" XIF "], %[uvIF], v[" XXP "], %[bvIF]\n\t" \
  "v_pk_fma_f32 v[" XGO "], %[uvGO], v[" XXP "], %[bvGO]\n\t" \
  "v_add_u32 " XXA ", 4, " XXA "\n\t" \
  "s_waitcnt lgkmcnt(3)\n\t" \
  GRP(XIF,XGO,"128:129","130:131","192:193","194:195",XP0) \
  GRP(XIF,XGO,"132:133","134:135","196:197","198:199",XP1) \
  "v_add_f32 v" YU0 ", 1.0, v" YU0 "\n\t" \
  "v_add_f32 v" YU1 ", 1.0, v" YU1 "\n\t" \
  "ds_read_b128 v[" XQ0 "], " XHR " offset:64\n\t" \
  "s_waitcnt lgkmcnt(3)\n\t" \
  GRP(XIF,XGO,"136:137","138:139","200:201","202:203",XP2) \
  GRP(XIF,XGO,"140:141","142:143","204:205","206:207",XP3) \
  "v_add_f32 v" YU2 ", 1.0, v" YU2 "\n\t" \
  "v_add_f32 v" YU3 ", 1.0, v" YU3 "\n\t" \
  "ds_read_b128 v[" XQ1 "], " XHR " offset:80\n\t" \
  "s_waitcnt lgkmcnt(3)\n\t" \
  GRP(XIF,XGO,"144:145","146:147","208:209","210:211",XP4) \
  GRP(XIF,XGO,"148:149","150:151","212:213","214:215",XP5) \
  "v_rcp_f32 v" YU0 ", v" YU0 "\n\t" \
  "v_rcp_f32 v" YU1 ", v" YU1 "\n\t" \
  "ds_read_b128 v[" XQ2 "], " XHR " offset:96\n\t" \
  "s_waitcnt lgkmcnt(3)\n\t" \
  GRP(XIF,XGO,"152:153","154:155","216:217","218:219",XP6) \
  GRP(XIF,XGO,"156:157","158:159","220:221","222:223",XP7) \
  "v_rcp_f32 v" YU2 ", v" YU2 "\n\t" \
  "v_rcp_f32 v" YU3 ", v" YU3 "\n\t" \
  "ds_read_b128 v[" XQ3 "], " XHR " offset:112\n\t" \
  "s_waitcnt lgkmcnt(3)\n\t" \
  GRP(XIF,XGO,"160:161","162:163","224:225","226:227",XP0) \
  GRP(XIF,XGO,"164:165","166:167","228:229","230:231",XP1) \
  "v_fma_f32 v" YU4 ", -2.0, v" YU2 ", 1.0\n\t" \
  "v_mul_f32 v" YU5 ", v" YU0 ", v" YU4 "\n\t" \
  "s_waitcnt lgkmcnt(2)\n\t" \
  GRP(XIF,XGO,"168:169","170:171","232:233","234:235",XP2) \
  GRP(XIF,XGO,"172:173","174:175","236:237","238:239",XP3) \
  "v_fma_f32 " YC ", v" YU1 ", " YC ", v" YU5 "\n\t" \
  "v_mul_f32 v" YU6 ", 0x4038aa3b, " YC "\n\t" \
  "s_waitcnt lgkmcnt(1)\n\t" \
  GRP(XIF,XGO,"176:177","178:179","240:241","242:243",XP4) \
  GRP(XIF,XGO,"180:181","182:183","244:245","246:247",XP5) \
  "v_exp_f32 v" YU6 ", v" YU6 "\n\t" \
  "s_waitcnt lgkmcnt(0)\n\t" \
  GRP(XIF,XGO,"184:185","186:187","248:249","250:251",XP6) \
  "v_add_f32 v" YU6 ", 1.0, v" YU6 "\n\t" \
  "v_rcp_f32 v" YU6 ", v" YU6 "\n\t" \
  GRP(XIF,XGO,"188:189","190:191","252:253","254:255",XP7) \
  "v_fma_f32 v" YU6 ", -2.0, v" YU6 ", 1.0\n\t" \
  "v_mul_f32 " YH ", v" YU3 ", v" YU6 "\n\t" \
  "ds_write_b32 " YHW ", " YH "\n\t" \
  "ds_read2_b32 v[" YXP "], " YXA " offset0:0 offset1:0\n\t" \
  "ds_read_b128 v[" YQ0 "], " YHR " offset:0\n\t" \
  "ds_read_b128 v[" YQ1 "], " YHR " offset:16\n\t" \
  "ds_read_b128 v[" YQ2 "], " YHR " offset:32\n\t" \
  "ds_read_b128 v[" YQ3 "], " YHR " offset:48\n\t"

// Variadic trampoline: lets the *_ARGS bundles prescan-expand into the full
// 37-argument list before SLOT's parameter-count check (round-11 fix).
#define SLOTX(...) SLOT(__VA_ARGS__)

// Prologue MAC for chain A only (no Y interleave); same waits/order.
#define PROMAC \
  "s_waitcnt lgkmcnt(4)\n\t" \
  "v_pk_fma_f32 v[80:81], %[uvIF], v[84:85], %[bvIF]\n\t" \
  "v_pk_fma_f32 v[82:83], %[uvGO], v[84:85], %[bvGO]\n\t" \
  "v_add_u32 %[xaA], 4, %[xaA]\n\t" \
  "s_waitcnt lgkmcnt(3)\n\t" \
  GRP("80:81","82:83","128:129","130:131","192:193","194:195","64:65") \
  GRP("80:81","82:83","132:133","134:135","196:197","198:199","66:67") \
  "ds_read_b128 v[64:67], %[hrA] offset:64\n\t" \
  "s_waitcnt lgkmcnt(3)\n\t" \
  GRP("80:81","82:83","136:137","138:139","200:201","202:203","68:69") \
  GRP("80:81","82:83","140:141","142:143","204:205","206:207","70:71") \
  "ds_read_b128 v[68:71], %[hrA] offset:80\n\t" \
  "s_waitcnt lgkmcnt(3)\n\t" \
  GRP("80:81","82:83","144:145","146:147","208:209","210:211","72:73") \
  GRP("80:81","82:83","148:149","150:151","212:213","214:215","74:75") \
  "ds_read_b128 v[72:75], %[hrA] offset:96\n\t" \
  "s_waitcnt lgkmcnt(3)\n\t" \
  GRP("80:81","82:83","152:153","154:155","216:217","218:219","76:77") \
  GRP("80:81","82:83","156:157","158:159","220:221","222:223","78:79") \
  "ds_read_b128 v[76:79], %[hrA] offset:112\n\t" \
  "s_waitcnt lgkmcnt(3)\n\t" \
  GRP("80:81","82:83","160:161","162:163","224:225","226:227","64:65") \
  GRP("80:81","82:83","164:165","166:167","228:229","230:231","66:67") \
  "s_waitcnt lgkmcnt(2)\n\t" \
  GRP("80:81","82:83","168:169","170:171","232:233","234:235","68:69") \
  GRP("80:81","82:83","172:173","174:175","236:237","238:239","70:71") \
  "s_waitcnt lgkmcnt(1)\n\t" \
  GRP("80:81","82:83","176:177","178:179","240:241","242:243","72:73") \
  GRP("80:81","82:83","180:181","182:183","244:245","246:247","74:75") \
  "s_waitcnt lgkmcnt(0)\n\t" \
  GRP("80:81","82:83","184:185","186:187","248:249","250:251","76:77") \
  GRP("80:81","82:83","188:189","190:191","252:253","254:255","78:79")

// Plain activation (epilogue, once): same op order/constants as rounds 6-10.
#define PLAINACT(YI,YF,YG,YO, YU0,YU1,YU2,YU3,YU4,YU5,YU6, YC,YH,YHW) \
  "v_mul_f32 v" YU0 ", 0xbfb8aa3b, v" YI "\n\t" \
  "v_mul_f32 v" YU1 ", 0xbfb8aa3b, v" YF "\n\t" \
  "v_mul_f32 v" YU2 ", 0x4038aa3b, v" YG "\n\t" \
  "v_mul_f32 v" YU3 ", 0xbfb8aa3b, v" YO "\n\t" \
  "v_exp_f32 v" YU0 ", v" YU0 "\n\t" \
  "v_exp_f32 v" YU1 ", v" YU1 "\n\t" \
  "v_exp_f32 v" YU2 ", v" YU2 "\n\t" \
  "v_exp_f32 v" YU3 ", v" YU3 "\n\t" \
  "s_nop 1\n\t" \
  "v_add_f32 v" YU0 ", 1.0, v" YU0 "\n\t" \
  "v_add_f32 v" YU1 ", 1.0, v" YU1 "\n\t" \
  "v_add_f32 v" YU2 ", 1.0, v" YU2 "\n\t" \
  "v_add_f32 v" YU3 ", 1.0, v" YU3 "\n\t" \
  "v_rcp_f32 v" YU0 ", v" YU0 "\n\t" \
  "v_rcp_f32 v" YU1 ", v" YU1 "\n\t" \
  "v_rcp_f32 v" YU2 ", v" YU2 "\n\t" \
  "v_rcp_f32 v" YU3 ", v" YU3 "\n\t" \
  "s_nop 1\n\t" \
  "v_fma_f32 v" YU4 ", -2.0, v" YU2 ", 1.0\n\t" \
  "v_mul_f32 v" YU5 ", v" YU0 ", v" YU4 "\n\t" \
  "v_fma_f32 " YC ", v" YU1 ", " YC ", v" YU5 "\n\t" \
  "v_mul_f32 v" YU6 ", 0x4038aa3b, " YC "\n\t" \
  "v_exp_f32 v" YU6 ", v" YU6 "\n\t" \
  "s_nop 1\n\t" \
  "v_add_f32 v" YU6 ", 1.0, v" YU6 "\n\t" \
  "v_rcp_f32 v" YU6 ", v" YU6 "\n\t" \
  "s_nop 1\n\t" \
  "v_fma_f32 v" YU6 ", -2.0, v" YU6 ", 1.0\n\t" \
  "v_mul_f32 " YH ", v" YU3 ", v" YU6 "\n\t" \
  "ds_write_b32 " YHW ", " YH "\n\t"

#define CLOBS \
  "v64","v65","v66","v67","v68","v69","v70","v71","v72","v73","v74","v75", \
  "v76","v77","v78","v79","v80","v81","v82","v83","v84","v85","v86","v87", \
  "v88","v89","v90","v91","v92","v93","v94","v95","v96","v97","v98","v99", \
  "v100","v101","v102","v103","v104","v105","v106","v107","v108","v109", \
  "v110","v111","v112","v113","v114","v115","v116","v117","v118","v119", \
  "v120","v121","v122","v123","v124","v125","v126","v127","v128","v129", \
  "v130","v131","v132","v133","v134","v135","v136","v137","v138","v139", \
  "v140","v141","v142","v143","v144","v145","v146","v147","v148","v149", \
  "v150","v151","v152","v153","v154","v155","v156","v157","v158","v159", \
  "v160","v161","v162","v163","v164","v165","v166","v167","v168","v169", \
  "v170","v171","v172","v173","v174","v175","v176","v177","v178","v179", \
  "v180","v181","v182","v183","v184","v185","v186","v187","v188","v189", \
  "v190","v191","v192","v193","v194","v195","v196","v197","v198","v199", \
  "v200","v201","v202","v203","v204","v205","v206","v207","v208","v209", \
  "v210","v211","v212","v213","v214","v215","v216","v217","v218","v219", \
  "v220","v221","v222","v223","v224","v225","v226","v227","v228","v229", \
  "v230","v231","v232","v233","v234","v235","v236","v237","v238","v239", \
  "v240","v241","v242","v243","v244","v245","v246","v247","v248","v249", \
  "v250","v251","v252","v253","v254","v255"

// SLOT argument bundles for the two chain roles.
#define XA_ARGS "80:81","82:83", "64:67","68:71","72:75","76:79", \
  "64:65","66:67","68:69","70:71","72:73","74:75","76:77","78:79", \
  "84:85", "%[xaA]", "%[hrA]"
#define XB_ARGS "112:113","114:115", "96:99","100:103","104:107","108:111", \
  "96:97","98:99","100:101","102:103","104:105","106:107","108:109","110:111", \
  "116:117", "%[xaB]", "%[hrB]"
#define YA_ARGS "80","81","82","83", "86","87","88","89","90","91","92", \
  "%[cA]","%[hA]", "%[hwA]", "84:85", "%[xaA]", "%[hrA]", \
  "64:67","68:71","72:75","76:79"
#define YB_ARGS "112","113","114","115", "118","119","120","121","122","123","124", \
  "%[cB]","%[hB]", "%[hwB]", "116:117", "%[xaB]", "%[hrB]", \
  "96:99","100:103","104:107","108:111"

__global__ __launch_bounds__(BLOCK)
void lstm_fused_kernel(
    const float* __restrict__ x,       // [B, T, 1]
    const float* __restrict__ W_ih,    // [4H, 1]
    const float* __restrict__ W_hh,    // [4H, H] row-major
    const float* __restrict__ b_ih,    // [4H]
    const float* __restrict__ b_hh,    // [4H]
    const float* __restrict__ W_head,  // [1, H]
    const float* __restrict__ b_head,  // [1]
    float* __restrict__ out)           // [B, 1]
{
    __shared__ __align__(16) v2f WIFL[32][34];
    __shared__ __align__(16) v2f WGOL[32][34];
    __shared__ __align__(16) float Xall[WAVES_PER_BLOCK][4][SEQ];   // 32 KB
    __shared__ __align__(16) float Hbuf[WAVES_PER_BLOCK][4][32];

    const int tid = threadIdx.x;
    for (int idx = tid; idx < 1024; idx += BLOCK) {
        const int u = idx >> 5;
        const int j = idx & 31;
        WIFL[u][j] = (v2f){ W_hh[u * 32 + j],        W_hh[(32 + u) * 32 + j] };
        WGOL[u][j] = (v2f){ W_hh[(64 + u) * 32 + j], W_hh[(96 + u) * 32 + j] };
    }
    // Stage ALL x for this block's 16 samples (coalesced; no global loads in loop).
    {
        const int base = blockIdx.x * 16;
        for (int idx = tid; idx < 16 * SEQ; idx += BLOCK) {
            const int smp = idx >> 9;          // 0..15 = wid*4 + cs
            const int t   = idx & (SEQ - 1);
            Xall[smp >> 2][smp & 3][t] = x[(size_t)(base + smp) * SEQ + t];
        }
    }
    __syncthreads();

    const int lane = tid & 63;
    const int u    = lane & 31;
    const int s    = lane >> 5;
    const int wid  = tid >> 6;
    const int bbase = blockIdx.x * 16 + wid * 4;

    // Preload shared weights into v128..v255 (once).
    {
        const unsigned aIF = (unsigned)(size_t)&WIFL[u][0];
        const unsigned aGO = (unsigned)(size_t)&WGOL[u][0];
        asm volatile(
            "ds_read_b128 v[128:131], %[wa] offset:0\n\t"
            "ds_read_b128 v[132:135], %[wa] offset:16\n\t"
            "ds_read_b128 v[136:139], %[wa] offset:32\n\t"
            "ds_read_b128 v[140:143], %[wa] offset:48\n\t"
            "ds_read_b128 v[144:147], %[wa] offset:64\n\t"
            "ds_read_b128 v[148:151], %[wa] offset:80\n\t"
            "ds_read_b128 v[152:155], %[wa] offset:96\n\t"
            "ds_read_b128 v[156:159], %[wa] offset:112\n\t"
            "ds_read_b128 v[160:163], %[wa] offset:128\n\t"
            "ds_read_b128 v[164:167], %[wa] offset:144\n\t"
            "ds_read_b128 v[168:171], %[wa] offset:160\n\t"
            "ds_read_b128 v[172:175], %[wa] offset:176\n\t"
            "ds_read_b128 v[176:179], %[wa] offset:192\n\t"
            "ds_read_b128 v[180:183], %[wa] offset:208\n\t"
            "ds_read_b128 v[184:187], %[wa] offset:224\n\t"
            "ds_read_b128 v[188:191], %[wa] offset:240\n\t"
            "ds_read_b128 v[192:195], %[wb] offset:0\n\t"
            "ds_read_b128 v[196:199], %[wb] offset:16\n\t"
            "ds_read_b128 v[200:203], %[wb] offset:32\n\t"
            "ds_read_b128 v[204:207], %[wb] offset:48\n\t"
            "ds_read_b128 v[208:211], %[wb] offset:64\n\t"
            "ds_read_b128 v[212:215], %[wb] offset:80\n\t"
            "ds_read_b128 v[216:219], %[wb] offset:96\n\t"
            "ds_read_b128 v[220:223], %[wb] offset:112\n\t"
            "ds_read_b128 v[224:227], %[wb] offset:128\n\t"
            "ds_read_b128 v[228:231], %[wb] offset:144\n\t"
            "ds_read_b128 v[232:235], %[wb] offset:160\n\t"
            "ds_read_b128 v[236:239], %[wb] offset:176\n\t"
            "ds_read_b128 v[240:243], %[wb] offset:192\n\t"
            "ds_read_b128 v[244:247], %[wb] offset:208\n\t"
            "ds_read_b128 v[248:251], %[wb] offset:224\n\t"
            "ds_read_b128 v[252:255], %[wb] offset:240\n\t"
            "s_waitcnt lgkmcnt(0)"
            :
            : [wa]"v"(aIF), [wb]"v"(aGO)
            : "memory", CLOBS);
    }

    const v2f bvIF = { b_ih[u]      + b_hh[u],      b_ih[32 + u] + b_hh[32 + u] };
    const v2f bvGO = { b_ih[64 + u] + b_hh[64 + u], b_ih[96 + u] + b_hh[96 + u] };
    const v2f uvIF = { W_ih[u],      W_ih[32 + u] };
    const v2f uvGO = { W_ih[64 + u], W_ih[96 + u] };

    const unsigned hrA = (unsigned)(size_t)&Hbuf[wid][s][0];
    const unsigned hwA = hrA + (unsigned)(u * 4);
    const unsigned hrB = (unsigned)(size_t)&Hbuf[wid][2 + s][0];
    const unsigned hwB = hrB + (unsigned)(u * 4);
    unsigned xaA = (unsigned)(size_t)&Xall[wid][s][0];
    unsigned xaB = (unsigned)(size_t)&Xall[wid][2 + s][0];

    float hA = 0.0f, cA = 0.0f, hB = 0.0f, cB = 0.0f;
    Hbuf[wid][s][u]     = 0.0f;   // wave-private rows: same-wave DS ordering
    Hbuf[wid][2 + s][u] = 0.0f;

    // Prologue: issue A reads, A-MAC(0), then issue B reads for the loop.
    asm volatile(
        "ds_read2_b32 v[84:85], %[xaA] offset0:0 offset1:0\n\t"
        "ds_read_b128 v[64:67], %[hrA] offset:0\n\t"
        "ds_read_b128 v[68:71], %[hrA] offset:16\n\t"
        "ds_read_b128 v[72:75], %[hrA] offset:32\n\t"
        "ds_read_b128 v[76:79], %[hrA] offset:48\n\t"
        PROMAC
        "ds_read2_b32 v[116:117], %[xaB] offset0:0 offset1:0\n\t"
        "ds_read_b128 v[96:99],   %[hrB] offset:0\n\t"
        "ds_read_b128 v[100:103], %[hrB] offset:16\n\t"
        "ds_read_b128 v[104:107], %[hrB] offset:32\n\t"
        "ds_read_b128 v[108:111], %[hrB] offset:48\n\t"
        : [xaA]"+v"(xaA), [xaB]"+v"(xaB)
        : [hrA]"v"(hrA), [hrB]"v"(hrB),
          [uvIF]"v"(uvIF), [bvIF]"v"(bvIF), [uvGO]"v"(uvGO), [bvGO]"v"(bvGO)
        : "memory", CLOBS);

    // Steady state: iteration t does [B-MAC(t) || A-act(t)], [A-MAC(t+1) || B-act(t)].
#pragma unroll 1
    for (int t = 0; t < SEQ - 1; ++t) {
        asm volatile(
            SLOTX(XB_ARGS, YA_ARGS)
            SLOTX(XA_ARGS, YB_ARGS)
            : [hA]"+v"(hA), [cA]"+v"(cA), [hB]"+v"(hB), [cB]"+v"(cB),
              [xaA]"+v"(xaA), [xaB]"+v"(xaB)
            : [hrA]"v"(hrA), [hrB]"v"(hrB), [hwA]"v"(hwA), [hwB]"v"(hwB),
              [uvIF]"v"(uvIF), [bvIF]"v"(bvIF), [uvGO]"v"(uvGO), [bvGO]"v"(bvGO)
            : "memory", CLOBS);
    }

    // Epilogue: [B-MAC(511) || A-act(511)], then plain B-act(511).
    asm volatile(
        SLOTX(XB_ARGS, YA_ARGS)
        PLAINACT("112","113","114","115", "118","119","120","121","122","123","124",
                 "%[cB]","%[hB]","%[hwB]")
        "s_waitcnt lgkmcnt(0)"
        : [hA]"+v"(hA), [cA]"+v"(cA), [hB]"+v"(hB), [cB]"+v"(cB),
          [xaA]"+v"(xaA), [xaB]"+v"(xaB)
        : [hrA]"v"(hrA), [hrB]"v"(hrB), [hwA]"v"(hwA), [hwB]"v"(hwB),
          [uvIF]"v"(uvIF), [bvIF]"v"(bvIF), [uvGO]"v"(uvGO), [bvGO]"v"(bvGO)
        : "memory", CLOBS);

    // Head for both chains: reductions stay within each 32-lane half.
    float vA = hA * W_head[u];
    float vB = hB * W_head[u];
#pragma unroll
    for (int off = 16; off >= 1; off >>= 1) {
        vA += __shfl_xor(vA, off);
        vB += __shfl_xor(vB, off);
    }
    if (u == 0) {
        out[bbase + s]     = vA + b_head[0];
        out[bbase + 2 + s] = vB + b_head[0];
    }
}

extern "C" void kernel_launch(void* const* d_in, const int* in_sizes, int n_in,
                              void* d_out, int out_size, void* d_ws, size_t ws_size,
                              hipStream_t stream) {
    const float* x      = (const float*)d_in[0];
    const float* W_ih   = (const float*)d_in[1];
    const float* W_hh   = (const float*)d_in[2];
    const float* b_ih   = (const float*)d_in[3];
    const float* b_hh   = (const float*)d_in[4];
    const float* W_head = (const float*)d_in[5];
    const float* b_head = (const float*)d_in[6];
    float* out = (float*)d_out;

    const int B = in_sizes[0] / SEQ;            // 4096
    const int grid = B / 16;                    // 256 blocks, 4 waves, 4 smp/wave

    lstm_fused_kernel<<<grid, BLOCK, 0, stream>>>(
        x, W_ih, W_hh, b_ih, b_hh, W_head, b_head, out);
}

// Round 13
// 316.177 us; speedup vs baseline: 1.0769x; 1.0769x over previous
//
#include <hip/hip_runtime.h>

#define HID 32
#define SEQ 512
#define WAVES_PER_BLOCK 8
#define BLOCK (WAVES_PER_BLOCK * 64)

typedef float v2f __attribute__((ext_vector_type(2)));

// ---------------------------------------------------------------------------
// BARRIER-ENFORCED ANTI-PHASE TLP-2.
// One wave = 2 samples (lane (s,u) owns all 4 gates of unit u of sample s;
// round-9 layout, absmax 0.0). 512-thread block = 8 waves; waves w and w+4
// share a SIMD. Even group (wid<4) and odd group (wid>=4) run the SAME per-
// sample op sequence but offset half a step, with s_barrier at every phase
// boundary:   phase1: even-MAC(t) || odd-ACT(t)
//             phase2: even-ACT(t) || odd-MAC(t+1)
// => each SIMD always pairs one issue-dense MAC with one latency-dominated
// ACT. Round 10 (uncoordinated TLP-2) measured 1261 cyc/CU-step vs ~950
// issue because phases collide; round 12 (ILP-2, 1 wave/SIMD) exposed all
// latency (60% busy). This schedule is the enforced version of what both
// were reaching for.
// MAC also now issues ALL 8 h-quads + x up front (quads v64-79 + v224-239;
// weights end at v223) with descending lgkm waits -- the late quads have
// hundreds of MAC cycles in flight above them, removing round-10's mid-step
// refill stalls.
// Register map: q0-3 v64-79, q4-7 v224-239, acc v80-83 (pi,pf,pg,po),
// x v84-85, act temps v86-92, weights (wi,wf)[j]=v[96+2j] (wg,wo)[j]=v[160+2j].
// ---------------------------------------------------------------------------

#define GRP(WA, WB, WC, WD, HP) \
  "v_pk_fma_f32 v[80:81], v[" WA "], " HP ", v[80:81] op_sel_hi:[1,0,1]\n\t" \
  "v_pk_fma_f32 v[82:83], v[" WC "], " HP ", v[82:83] op_sel_hi:[1,0,1]\n\t" \
  "v_pk_fma_f32 v[80:81], v[" WB "], " HP ", v[80:81] op_sel:[0,1,0] op_sel_hi:[1,1,1]\n\t" \
  "v_pk_fma_f32 v[82:83], v[" WD "], " HP ", v[82:83] op_sel:[0,1,0] op_sel_hi:[1,1,1]\n\t"

#define CLOBS \
  "v64","v65","v66","v67","v68","v69","v70","v71","v72","v73","v74","v75", \
  "v76","v77","v78","v79","v80","v81","v82","v83","v84","v85","v86","v87", \
  "v88","v89","v90","v91","v92","v93","v94","v95","v96","v97","v98","v99", \
  "v100","v101","v102","v103","v104","v105","v106","v107","v108","v109", \
  "v110","v111","v112","v113","v114","v115","v116","v117","v118","v119", \
  "v120","v121","v122","v123","v124","v125","v126","v127","v128","v129", \
  "v130","v131","v132","v133","v134","v135","v136","v137","v138","v139", \
  "v140","v141","v142","v143","v144","v145","v146","v147","v148","v149", \
  "v150","v151","v152","v153","v154","v155","v156","v157","v158","v159", \
  "v160","v161","v162","v163","v164","v165","v166","v167","v168","v169", \
  "v170","v171","v172","v173","v174","v175","v176","v177","v178","v179", \
  "v180","v181","v182","v183","v184","v185","v186","v187","v188","v189", \
  "v190","v191","v192","v193","v194","v195","v196","v197","v198","v199", \
  "v200","v201","v202","v203","v204","v205","v206","v207","v208","v209", \
  "v210","v211","v212","v213","v214","v215","v216","v217","v218","v219", \
  "v220","v221","v222","v223","v224","v225","v226","v227","v228","v229", \
  "v230","v231","v232","v233","v234","v235","v236","v237","v238","v239"

// MAC(t): 9 DS reads up front, then 66 pk_fma with descending lgkm waits.
// Acc left in v80-83. x addr advances 4 B. All ops/order match round 9/10.
#define MAC_ASM(XA) \
    asm volatile( \
        "ds_read2_b32 v[84:85], %[xa] offset0:0 offset1:0\n\t" \
        "ds_read_b128 v[64:67],   %[hr] offset:0\n\t" \
        "ds_read_b128 v[68:71],   %[hr] offset:16\n\t" \
        "ds_read_b128 v[72:75],   %[hr] offset:32\n\t" \
        "ds_read_b128 v[76:79],   %[hr] offset:48\n\t" \
        "ds_read_b128 v[224:227], %[hr] offset:64\n\t" \
        "ds_read_b128 v[228:231], %[hr] offset:80\n\t" \
        "ds_read_b128 v[232:235], %[hr] offset:96\n\t" \
        "ds_read_b128 v[236:239], %[hr] offset:112\n\t" \
        "v_add_u32 %[xa], 4, %[xa]\n\t" \
        "s_waitcnt lgkmcnt(8)\n\t" \
        "v_pk_fma_f32 v[80:81], %[uvIF], v[84:85], %[bvIF]\n\t" \
        "v_pk_fma_f32 v[82:83], %[uvGO], v[84:85], %[bvGO]\n\t" \
        "s_waitcnt lgkmcnt(7)\n\t" \
        GRP("96:97","98:99","160:161","162:163","v[64:65]") \
        GRP("100:101","102:103","164:165","166:167","v[66:67]") \
        "s_waitcnt lgkmcnt(6)\n\t" \
        GRP("104:105","106:107","168:169","170:171","v[68:69]") \
        GRP("108:109","110:111","172:173","174:175","v[70:71]") \
        "s_waitcnt lgkmcnt(5)\n\t" \
        GRP("112:113","114:115","176:177","178:179","v[72:73]") \
        GRP("116:117","118:119","180:181","182:183","v[74:75]") \
        "s_waitcnt lgkmcnt(4)\n\t" \
        GRP("120:121","122:123","184:185","186:187","v[76:77]") \
        GRP("124:125","126:127","188:189","190:191","v[78:79]") \
        "s_waitcnt lgkmcnt(3)\n\t" \
        GRP("128:129","130:131","192:193","194:195","v[224:225]") \
        GRP("132:133","134:135","196:197","198:199","v[226:227]") \
        "s_waitcnt lgkmcnt(2)\n\t" \
        GRP("136:137","138:139","200:201","202:203","v[228:229]") \
        GRP("140:141","142:143","204:205","206:207","v[230:231]") \
        "s_waitcnt lgkmcnt(1)\n\t" \
        GRP("144:145","146:147","208:209","210:211","v[232:233]") \
        GRP("148:149","150:151","212:213","214:215","v[234:235]") \
        "s_waitcnt lgkmcnt(0)\n\t" \
        GRP("152:153","154:155","216:217","218:219","v[236:237]") \
        GRP("156:157","158:159","220:221","222:223","v[238:239]") \
        : [xa]"+v"(XA) \
        : [hr]"v"(hr), [uvIF]"v"(uvIF), [bvIF]"v"(bvIF), \
          [uvGO]"v"(uvGO), [bvGO]"v"(bvGO) \
        : "memory", CLOBS)

// ACT(t): activation chain from acc v80-83 -> c,h; write h. Byte-identical
// op order/constants to rounds 9/10 (absmax 0.0).
#define ACT_ASM() \
    asm volatile( \
        "v_mul_f32 v86, 0xbfb8aa3b, v80\n\t" \
        "v_mul_f32 v87, 0xbfb8aa3b, v81\n\t" \
        "v_mul_f32 v88, 0x4038aa3b, v82\n\t" \
        "v_mul_f32 v89, 0xbfb8aa3b, v83\n\t" \
        "v_exp_f32 v86, v86\n\t" \
        "v_exp_f32 v87, v87\n\t" \
        "v_exp_f32 v88, v88\n\t" \
        "v_exp_f32 v89, v89\n\t" \
        "v_add_f32 v86, 1.0, v86\n\t" \
        "v_add_f32 v87, 1.0, v87\n\t" \
        "v_add_f32 v88, 1.0, v88\n\t" \
        "v_add_f32 v89, 1.0, v89\n\t" \
        "v_rcp_f32 v86, v86\n\t" \
        "v_rcp_f32 v87, v87\n\t" \
        "v_rcp_f32 v88, v88\n\t" \
        "v_rcp_f32 v89, v89\n\t" \
        "s_nop 1\n\t" \
        "v_fma_f32 v90, -2.0, v88, 1.0\n\t" \
        "v_mul_f32 v91, v86, v90\n\t" \
        "v_fma_f32 %[c], v87, %[c], v91\n\t" \
        "v_mul_f32 v92, 0x4038aa3b, %[c]\n\t" \
        "v_exp_f32 v92, v92\n\t" \
        "s_nop 1\n\t" \
        "v_add_f32 v92, 1.0, v92\n\t" \
        "v_rcp_f32 v92, v92\n\t" \
        "s_nop 1\n\t" \
        "v_fma_f32 v92, -2.0, v92, 1.0\n\t" \
        "v_mul_f32 %[h], v89, v92\n\t" \
        "ds_write_b32 %[hw], %[h]\n\t" \
        : [h]"+v"(h), [c]"+v"(c) \
        : [hw]"v"(hw) \
        : "memory", CLOBS)

#define BAR() __builtin_amdgcn_s_barrier()

__global__ __launch_bounds__(BLOCK)
void lstm_fused_kernel(
    const float* __restrict__ x,       // [B, T, 1]
    const float* __restrict__ W_ih,    // [4H, 1]
    const float* __restrict__ W_hh,    // [4H, H] row-major
    const float* __restrict__ b_ih,    // [4H]
    const float* __restrict__ b_hh,    // [4H]
    const float* __restrict__ W_head,  // [1, H]
    const float* __restrict__ b_head,  // [1]
    float* __restrict__ out)           // [B, 1]
{
    __shared__ __align__(16) v2f WIFL[32][34];
    __shared__ __align__(16) v2f WGOL[32][34];
    __shared__ __align__(16) float Xall[WAVES_PER_BLOCK][2][SEQ];   // 32 KB
    __shared__ __align__(16) float Hbuf[WAVES_PER_BLOCK][2][32];

    const int tid = threadIdx.x;
    for (int idx = tid; idx < 1024; idx += BLOCK) {
        const int u = idx >> 5;
        const int j = idx & 31;
        WIFL[u][j] = (v2f){ W_hh[u * 32 + j],        W_hh[(32 + u) * 32 + j] };
        WGOL[u][j] = (v2f){ W_hh[(64 + u) * 32 + j], W_hh[(96 + u) * 32 + j] };
    }
    // Stage all x for this block's 16 samples (coalesced).
    {
        const int base = blockIdx.x * 16;
        for (int idx = tid; idx < 16 * SEQ; idx += BLOCK) {
            const int smp = idx >> 9;          // 0..15 = wid*2 + s
            const int t   = idx & (SEQ - 1);
            Xall[smp >> 1][smp & 1][t] = x[(size_t)(base + smp) * SEQ + t];
        }
    }
    __syncthreads();

    const int lane = tid & 63;
    const int u    = lane & 31;
    const int s    = lane >> 5;
    const int wid  = tid >> 6;
    const bool even = (wid < 4);       // waves w and w+4 share a SIMD

    // Preload weights into v96..v223 (once; persist across asm blocks —
    // every asm block clobbers the range so the compiler never touches it).
    {
        const unsigned aIF = (unsigned)(size_t)&WIFL[u][0];
        const unsigned aGO = (unsigned)(size_t)&WGOL[u][0];
        asm volatile(
            "ds_read_b128 v[96:99],   %[wa] offset:0\n\t"
            "ds_read_b128 v[100:103], %[wa] offset:16\n\t"
            "ds_read_b128 v[104:107], %[wa] offset:32\n\t"
            "ds_read_b128 v[108:111], %[wa] offset:48\n\t"
            "ds_read_b128 v[112:115], %[wa] offset:64\n\t"
            "ds_read_b128 v[116:119], %[wa] offset:80\n\t"
            "ds_read_b128 v[120:123], %[wa] offset:96\n\t"
            "ds_read_b128 v[124:127], %[wa] offset:112\n\t"
            "ds_read_b128 v[128:131], %[wa] offset:128\n\t"
            "ds_read_b128 v[132:135], %[wa] offset:144\n\t"
            "ds_read_b128 v[136:139], %[wa] offset:160\n\t"
            "ds_read_b128 v[140:143], %[wa] offset:176\n\t"
            "ds_read_b128 v[144:147], %[wa] offset:192\n\t"
            "ds_read_b128 v[148:151], %[wa] offset:208\n\t"
            "ds_read_b128 v[152:155], %[wa] offset:224\n\t"
            "ds_read_b128 v[156:159], %[wa] offset:240\n\t"
            "ds_read_b128 v[160:163], %[wb] offset:0\n\t"
            "ds_read_b128 v[164:167], %[wb] offset:16\n\t"
            "ds_read_b128 v[168:171], %[wb] offset:32\n\t"
            "ds_read_b128 v[172:175], %[wb] offset:48\n\t"
            "ds_read_b128 v[176:179], %[wb] offset:64\n\t"
            "ds_read_b128 v[180:183], %[wb] offset:80\n\t"
            "ds_read_b128 v[184:187], %[wb] offset:96\n\t"
            "ds_read_b128 v[188:191], %[wb] offset:112\n\t"
            "ds_read_b128 v[192:195], %[wb] offset:128\n\t"
            "ds_read_b128 v[196:199], %[wb] offset:144\n\t"
            "ds_read_b128 v[200:203], %[wb] offset:160\n\t"
            "ds_read_b128 v[204:207], %[wb] offset:176\n\t"
            "ds_read_b128 v[208:211], %[wb] offset:192\n\t"
            "ds_read_b128 v[212:215], %[wb] offset:208\n\t"
            "ds_read_b128 v[216:219], %[wb] offset:224\n\t"
            "ds_read_b128 v[220:223], %[wb] offset:240\n\t"
            "s_waitcnt lgkmcnt(0)"
            :
            : [wa]"v"(aIF), [wb]"v"(aGO)
            : "memory", CLOBS);
    }

    const v2f bvIF = { b_ih[u]      + b_hh[u],      b_ih[32 + u] + b_hh[32 + u] };
    const v2f bvGO = { b_ih[64 + u] + b_hh[64 + u], b_ih[96 + u] + b_hh[96 + u] };
    const v2f uvIF = { W_ih[u],      W_ih[32 + u] };
    const v2f uvGO = { W_ih[64 + u], W_ih[96 + u] };

    const unsigned hr = (unsigned)(size_t)&Hbuf[wid][s][0];
    const unsigned hw = hr + (unsigned)(u * 4);
    unsigned xa = (unsigned)(size_t)&Xall[wid][s][0];

    float h = 0.0f, c = 0.0f;
    Hbuf[wid][s][u] = 0.0f;   // h(0); wave-private row, same-wave DS in-order
    __syncthreads();          // h(0) + staging visible before phase engine

    // ---- anti-phase engine: 1024 matched barriers per wave ----
    if (even) {
        BAR();                                   // #1 (odd runs MAC(0))
#pragma unroll 1
        for (int t = 0; t < SEQ - 1; ++t) {
            MAC_ASM(xa);  BAR();                 // phase1: MAC(t) || odd ACT(t)
            ACT_ASM();    BAR();                 // phase2: ACT(t) || odd MAC(t+1)
        }
        MAC_ASM(xa);  BAR();                     // #1024: MAC(511) || odd ACT(511)
        ACT_ASM();                               // tail, odd already done
    } else {
        MAC_ASM(xa);  BAR();                     // #1: MAC(0)
#pragma unroll 1
        for (int t = 0; t < SEQ - 1; ++t) {
            ACT_ASM();    BAR();                 // ACT(t)   || even MAC(t)... (offset)
            MAC_ASM(xa);  BAR();                 // MAC(t+1) || even ACT(t)
        }
        ACT_ASM();  BAR();                       // #1024: ACT(511) || even MAC(511)
    }

    // head: out = sum_u h[u]*W_head[u] + b_head; reduce within each half.
    float v = h * W_head[u];
#pragma unroll
    for (int off = 16; off >= 1; off >>= 1)
        v += __shfl_xor(v, off);
    if (u == 0) out[blockIdx.x * 16 + wid * 2 + s] = v + b_head[0];
}

extern "C" void kernel_launch(void* const* d_in, const int* in_sizes, int n_in,
                              void* d_out, int out_size, void* d_ws, size_t ws_size,
                              hipStream_t stream) {
    const float* x      = (const float*)d_in[0];
    const float* W_ih   = (const float*)d_in[1];
    const float* W_hh   = (const float*)d_in[2];
    const float* b_ih   = (const float*)d_in[3];
    const float* b_hh   = (const float*)d_in[4];
    const float* W_head = (const float*)d_in[5];
    const float* b_head = (const float*)d_in[6];
    float* out = (float*)d_out;

    const int B = in_sizes[0] / SEQ;            // 4096
    const int grid = B / 16;                    // 256 blocks x 8 waves x 2 smp

    lstm_fused_kernel<<<grid, BLOCK, 0, stream>>>(
        x, W_ih, W_hh, b_ih, b_hh, W_head, b_head, out);
}

// Round 14
// 278.170 us; speedup vs baseline: 1.2240x; 1.1366x over previous
//
#include <hip/hip_runtime.h>

#define HID 32
#define SEQ 512
#define WAVES_PER_BLOCK 4
#define BLOCK (WAVES_PER_BLOCK * 64)

typedef float v2f __attribute__((ext_vector_type(2)));

// ---------------------------------------------------------------------------
// Round-9/10 structure (269 us best): ONE WAVE = TWO SAMPLES, lane (s,u) owns
// all 4 gates of unit u of sample s; 128 weight floats/lane persistent in
// v96..v223. 2 waves/SIMD (launch-limited).
// Round-14 deltas:
//  (1) s_setprio 1 around the MAC, 0 around the ACT: when the SIMD's two
//      waves are at different phases, the MAC wave takes the issue slots the
//      latency-bound ACT wave cannot use -> self-organizing anti-phase with
//      zero barriers (the mechanism round 13's barriers paid ~78 cyc/step
//      for, and round 10's s_sleep could not pin).
//  (2) all 8 h-quads issued up-front with descending lgkm waits (q4-7 in
//      v224-239) -> later quads have hundreds of MAC cycles in flight above
//      them; no mid-step refill stalls.
//  (3) all x staged to LDS once (16 KB); dropped the null prefetch/stagger.
// Per-step instruction multiset identical to round 10 -> absmax 0.0.
// Register map: q0-3 v64-79, q4-7 v224-239, acc v80-83 (pi,pf | pg,po),
// x v84-85, act temps v86-92, weights (wi,wf)[j]=v[96+2j], (wg,wo)[j]=v[160+2j].
// ---------------------------------------------------------------------------

#define GRP(WA, WB, WC, WD, HP) \
  "v_pk_fma_f32 v[80:81], v[" WA "], " HP ", v[80:81] op_sel_hi:[1,0,1]\n\t" \
  "v_pk_fma_f32 v[82:83], v[" WC "], " HP ", v[82:83] op_sel_hi:[1,0,1]\n\t" \
  "v_pk_fma_f32 v[80:81], v[" WB "], " HP ", v[80:81] op_sel:[0,1,0] op_sel_hi:[1,1,1]\n\t" \
  "v_pk_fma_f32 v[82:83], v[" WD "], " HP ", v[82:83] op_sel:[0,1,0] op_sel_hi:[1,1,1]\n\t"

#define PKIF(E, O, HP) \
  "v_pk_fma_f32 v[80:81], v[" E "], " HP ", v[80:81] op_sel_hi:[1,0,1]\n\t" \
  "v_pk_fma_f32 v[80:81], v[" O "], " HP ", v[80:81] op_sel:[0,1,0] op_sel_hi:[1,1,1]\n\t"
#define PKGO(E, O, HP) \
  "v_pk_fma_f32 v[82:83], v[" E "], " HP ", v[82:83] op_sel_hi:[1,0,1]\n\t" \
  "v_pk_fma_f32 v[82:83], v[" O "], " HP ", v[82:83] op_sel:[0,1,0] op_sel_hi:[1,1,1]\n\t"

// One timestep. Prior step's h-write may be outstanding at entry: it only
// makes the first wait stricter (retired together with the x read2), never
// looser -- same-wave DS is in-order.
#define STEP \
  "s_setprio 1\n\t" \
  "ds_read2_b32 v[84:85], %[xa] offset0:0 offset1:0\n\t" \
  "ds_read_b128 v[64:67],   %[hr] offset:0\n\t" \
  "ds_read_b128 v[68:71],   %[hr] offset:16\n\t" \
  "ds_read_b128 v[72:75],   %[hr] offset:32\n\t" \
  "ds_read_b128 v[76:79],   %[hr] offset:48\n\t" \
  "ds_read_b128 v[224:227], %[hr] offset:64\n\t" \
  "ds_read_b128 v[228:231], %[hr] offset:80\n\t" \
  "ds_read_b128 v[232:235], %[hr] offset:96\n\t" \
  "ds_read_b128 v[236:239], %[hr] offset:112\n\t" \
  "v_add_u32 %[xa], 4, %[xa]\n\t" \
  "s_waitcnt lgkmcnt(8)\n\t" \
  "v_pk_fma_f32 v[80:81], %[uvIF], v[84:85], %[bvIF]\n\t" \
  "v_pk_fma_f32 v[82:83], %[uvGO], v[84:85], %[bvGO]\n\t" \
  "s_waitcnt lgkmcnt(7)\n\t" \
  GRP("96:97","98:99","160:161","162:163","v[64:65]") \
  GRP("100:101","102:103","164:165","166:167","v[66:67]") \
  "s_waitcnt lgkmcnt(6)\n\t" \
  GRP("104:105","106:107","168:169","170:171","v[68:69]") \
  GRP("108:109","110:111","172:173","174:175","v[70:71]") \
  "s_waitcnt lgkmcnt(5)\n\t" \
  GRP("112:113","114:115","176:177","178:179","v[72:73]") \
  GRP("116:117","118:119","180:181","182:183","v[74:75]") \
  "s_waitcnt lgkmcnt(4)\n\t" \
  GRP("120:121","122:123","184:185","186:187","v[76:77]") \
  GRP("124:125","126:127","188:189","190:191","v[78:79]") \
  "s_waitcnt lgkmcnt(3)\n\t" \
  GRP("128:129","130:131","192:193","194:195","v[224:225]") \
  GRP("132:133","134:135","196:197","198:199","v[226:227]") \
  "s_waitcnt lgkmcnt(2)\n\t" \
  GRP("136:137","138:139","200:201","202:203","v[228:229]") \
  GRP("140:141","142:143","204:205","206:207","v[230:231]") \
  "s_waitcnt lgkmcnt(1)\n\t" \
  GRP("144:145","146:147","208:209","210:211","v[232:233]") \
  GRP("148:149","150:151","212:213","214:215","v[234:235]") \
  "s_waitcnt lgkmcnt(0)\n\t" \
  /* tail reorder (round 10): finish IF, launch sigma(i,f), then GO */ \
  PKIF("152:153","154:155","v[236:237]") \
  PKIF("156:157","158:159","v[238:239]") \
  "v_mul_f32 v86, 0xbfb8aa3b, v80\n\t" \
  "v_exp_f32 v86, v86\n\t" \
  "v_mul_f32 v87, 0xbfb8aa3b, v81\n\t" \
  "v_exp_f32 v87, v87\n\t" \
  PKGO("216:217","218:219","v[236:237]") \
  PKGO("220:221","222:223","v[238:239]") \
  "s_setprio 0\n\t" \
  "v_mul_f32 v88, 0x4038aa3b, v82\n\t" \
  "v_exp_f32 v88, v88\n\t" \
  "v_mul_f32 v89, 0xbfb8aa3b, v83\n\t" \
  "v_exp_f32 v89, v89\n\t" \
  "v_add_f32 v86, 1.0, v86\n\t" \
  "v_add_f32 v87, 1.0, v87\n\t" \
  "v_add_f32 v88, 1.0, v88\n\t" \
  "v_add_f32 v89, 1.0, v89\n\t" \
  "v_rcp_f32 v86, v86\n\t" \
  "v_rcp_f32 v87, v87\n\t" \
  "v_rcp_f32 v88, v88\n\t" \
  "v_rcp_f32 v89, v89\n\t" \
  "s_nop 1\n\t" \
  "v_fma_f32 v90, -2.0, v88, 1.0\n\t" \
  "v_mul_f32 v91, v86, v90\n\t" \
  "v_fma_f32 %[c], v87, %[c], v91\n\t" \
  "v_mul_f32 v92, 0x4038aa3b, %[c]\n\t" \
  "v_exp_f32 v92, v92\n\t" \
  "s_nop 1\n\t" \
  "v_add_f32 v92, 1.0, v92\n\t" \
  "v_rcp_f32 v92, v92\n\t" \
  "s_nop 1\n\t" \
  "v_fma_f32 v92, -2.0, v92, 1.0\n\t" \
  "v_mul_f32 %[h], v89, v92\n\t" \
  "ds_write_b32 %[hw], %[h]\n\t"

#define S4  STEP STEP STEP STEP
#define X32 S4 S4 S4 S4 S4 S4 S4 S4

#define CLOBS \
  "v64","v65","v66","v67","v68","v69","v70","v71","v72","v73","v74","v75", \
  "v76","v77","v78","v79","v80","v81","v82","v83","v84","v85","v86","v87", \
  "v88","v89","v90","v91","v92","v93","v94","v95","v96","v97","v98","v99", \
  "v100","v101","v102","v103","v104","v105","v106","v107","v108","v109", \
  "v110","v111","v112","v113","v114","v115","v116","v117","v118","v119", \
  "v120","v121","v122","v123","v124","v125","v126","v127","v128","v129", \
  "v130","v131","v132","v133","v134","v135","v136","v137","v138","v139", \
  "v140","v141","v142","v143","v144","v145","v146","v147","v148","v149", \
  "v150","v151","v152","v153","v154","v155","v156","v157","v158","v159", \
  "v160","v161","v162","v163","v164","v165","v166","v167","v168","v169", \
  "v170","v171","v172","v173","v174","v175","v176","v177","v178","v179", \
  "v180","v181","v182","v183","v184","v185","v186","v187","v188","v189", \
  "v190","v191","v192","v193","v194","v195","v196","v197","v198","v199", \
  "v200","v201","v202","v203","v204","v205","v206","v207","v208","v209", \
  "v210","v211","v212","v213","v214","v215","v216","v217","v218","v219", \
  "v220","v221","v222","v223","v224","v225","v226","v227","v228","v229", \
  "v230","v231","v232","v233","v234","v235","v236","v237","v238","v239"

__global__ __launch_bounds__(BLOCK)
void lstm_fused_kernel(
    const float* __restrict__ x,       // [B, T, 1]
    const float* __restrict__ W_ih,    // [4H, 1]
    const float* __restrict__ W_hh,    // [4H, H] row-major
    const float* __restrict__ b_ih,    // [4H]
    const float* __restrict__ b_hh,    // [4H]
    const float* __restrict__ W_head,  // [1, H]
    const float* __restrict__ b_head,  // [1]
    float* __restrict__ out)           // [B, 1]
{
    __shared__ __align__(16) v2f WIFL[32][34];
    __shared__ __align__(16) v2f WGOL[32][34];
    __shared__ __align__(16) float Xall[WAVES_PER_BLOCK][2][SEQ];   // 16 KB
    __shared__ __align__(16) float Hbuf[WAVES_PER_BLOCK][2][32];

    const int tid = threadIdx.x;
    for (int idx = tid; idx < 1024; idx += BLOCK) {
        const int u = idx >> 5;
        const int j = idx & 31;
        WIFL[u][j] = (v2f){ W_hh[u * 32 + j],        W_hh[(32 + u) * 32 + j] };
        WGOL[u][j] = (v2f){ W_hh[(64 + u) * 32 + j], W_hh[(96 + u) * 32 + j] };
    }
    // Stage all x for this block's 8 samples once (coalesced).
    {
        const int base = blockIdx.x * 8;
        for (int idx = tid; idx < 8 * SEQ; idx += BLOCK) {
            const int smp = idx >> 9;          // 0..7 = wid*2 + s
            const int t   = idx & (SEQ - 1);
            Xall[smp >> 1][smp & 1][t] = x[(size_t)(base + smp) * SEQ + t];
        }
    }
    __syncthreads();

    const int lane = tid & 63;
    const int u    = lane & 31;
    const int s    = lane >> 5;
    const int wid  = tid >> 6;
    const int b0   = blockIdx.x * 8 + wid * 2;

    // Preload weights into persistent v96..v223 (once; every asm block
    // clobbers the range so the compiler never allocates there).
    {
        const unsigned aIF = (unsigned)(size_t)&WIFL[u][0];
        const unsigned aGO = (unsigned)(size_t)&WGOL[u][0];
        asm volatile(
            "ds_read_b128 v[96:99],   %[wa] offset:0\n\t"
            "ds_read_b128 v[100:103], %[wa] offset:16\n\t"
            "ds_read_b128 v[104:107], %[wa] offset:32\n\t"
            "ds_read_b128 v[108:111], %[wa] offset:48\n\t"
            "ds_read_b128 v[112:115], %[wa] offset:64\n\t"
            "ds_read_b128 v[116:119], %[wa] offset:80\n\t"
            "ds_read_b128 v[120:123], %[wa] offset:96\n\t"
            "ds_read_b128 v[124:127], %[wa] offset:112\n\t"
            "ds_read_b128 v[128:131], %[wa] offset:128\n\t"
            "ds_read_b128 v[132:135], %[wa] offset:144\n\t"
            "ds_read_b128 v[136:139], %[wa] offset:160\n\t"
            "ds_read_b128 v[140:143], %[wa] offset:176\n\t"
            "ds_read_b128 v[144:147], %[wa] offset:192\n\t"
            "ds_read_b128 v[148:151], %[wa] offset:208\n\t"
            "ds_read_b128 v[152:155], %[wa] offset:224\n\t"
            "ds_read_b128 v[156:159], %[wa] offset:240\n\t"
            "ds_read_b128 v[160:163], %[wb] offset:0\n\t"
            "ds_read_b128 v[164:167], %[wb] offset:16\n\t"
            "ds_read_b128 v[168:171], %[wb] offset:32\n\t"
            "ds_read_b128 v[172:175], %[wb] offset:48\n\t"
            "ds_read_b128 v[176:179], %[wb] offset:64\n\t"
            "ds_read_b128 v[180:183], %[wb] offset:80\n\t"
            "ds_read_b128 v[184:187], %[wb] offset:96\n\t"
            "ds_read_b128 v[188:191], %[wb] offset:112\n\t"
            "ds_read_b128 v[192:195], %[wb] offset:128\n\t"
            "ds_read_b128 v[196:199], %[wb] offset:144\n\t"
            "ds_read_b128 v[200:203], %[wb] offset:160\n\t"
            "ds_read_b128 v[204:207], %[wb] offset:176\n\t"
            "ds_read_b128 v[208:211], %[wb] offset:192\n\t"
            "ds_read_b128 v[212:215], %[wb] offset:208\n\t"
            "ds_read_b128 v[216:219], %[wb] offset:224\n\t"
            "ds_read_b128 v[220:223], %[wb] offset:240\n\t"
            "s_waitcnt lgkmcnt(0)"
            :
            : [wa]"v"(aIF), [wb]"v"(aGO)
            : "memory", CLOBS);
    }

    const v2f bvIF = { b_ih[u]      + b_hh[u],      b_ih[32 + u] + b_hh[32 + u] };
    const v2f bvGO = { b_ih[64 + u] + b_hh[64 + u], b_ih[96 + u] + b_hh[96 + u] };
    const v2f uvIF = { W_ih[u],      W_ih[32 + u] };
    const v2f uvGO = { W_ih[64 + u], W_ih[96 + u] };

    const unsigned hr = (unsigned)(size_t)&Hbuf[wid][s][0];
    const unsigned hw = hr + (unsigned)(u * 4);
    unsigned xa = (unsigned)(size_t)&Xall[wid][s][0];

    float h = 0.0f, c = 0.0f;
    Hbuf[wid][s][u] = 0.0f;   // h(0); wave-private row, same-wave DS in-order

#pragma unroll 1
    for (int t0 = 0; t0 < SEQ; t0 += 32) {
        asm volatile(
            X32
            : [h]"+v"(h), [c]"+v"(c), [xa]"+v"(xa)
            : [hr]"v"(hr), [hw]"v"(hw),
              [uvIF]"v"(uvIF), [bvIF]"v"(bvIF),
              [uvGO]"v"(uvGO), [bvGO]"v"(bvGO)
            : "memory", CLOBS);
    }

    // head: out[b0+s] = sum_u h[u]*W_head[u] + b_head (xor<32 stays per-half)
    float v = h * W_head[u];
#pragma unroll
    for (int off = 16; off >= 1; off >>= 1)
        v += __shfl_xor(v, off);
    if (u == 0) out[b0 + s] = v + b_head[0];
}

extern "C" void kernel_launch(void* const* d_in, const int* in_sizes, int n_in,
                              void* d_out, int out_size, void* d_ws, size_t ws_size,
                              hipStream_t stream) {
    const float* x      = (const float*)d_in[0];
    const float* W_ih   = (const float*)d_in[1];
    const float* W_hh   = (const float*)d_in[2];
    const float* b_ih   = (const float*)d_in[3];
    const float* b_hh   = (const float*)d_in[4];
    const float* W_head = (const float*)d_in[5];
    const float* b_head = (const float*)d_in[6];
    float* out = (float*)d_out;

    const int B = in_sizes[0] / SEQ;            // 4096
    const int grid = B / 8;                     // 512 blocks, 4 waves, 2 smp/wave

    lstm_fused_kernel<<<grid, BLOCK, 0, stream>>>(
        x, W_ih, W_hh, b_ih, b_hh, W_head, b_head, out);
}